// Round 10
// baseline (2047.307 us; speedup 1.0000x reference)
//
#include <hip/hip_runtime.h>
#include <hip/hip_bf16.h>

#pragma clang fp contract(off)

#define TT 512
#define CC 256
#define TPAD 257
#define INFV 1e9f

__device__ __forceinline__ unsigned long long packkey(float v, unsigned c) {
  return ((unsigned long long)__float_as_uint(v) << 32) | (unsigned long long)c;
}

__device__ __forceinline__ unsigned long long wave_min_u64(unsigned long long k) {
#pragma unroll
  for (int off = 32; off >= 1; off >>= 1) {
    unsigned long long o = __shfl_xor(k, off, 64);
    if (o < k) k = o;
  }
  return k;
}

// ---------------- Phase 1: distance matrix + initial row-min keys ----------------
// (unchanged — measured ~520 us, absmax 0.0; agglom changes isolated)
__device__ void load_norm_tile(const float* __restrict__ xb, int rowBase,
                               float (*S)[TPAD], double* part, int tid) {
  for (int idx = tid; idx < 64 * CC; idx += 256) {
    int r = idx >> 8;
    int c = idx & (CC - 1);
    S[r][c] = xb[(size_t)(rowBase + r) * CC + c];
  }
  __syncthreads();
  {
    int r = tid >> 2, p = tid & 3;
    double s = 0.0;
    int c0 = p * 64;
    for (int c = 0; c < 64; ++c) {
      double v = (double)S[r][c0 + c];
      s = fma(v, v, s);
    }
    part[tid] = s;
  }
  __syncthreads();
  if ((tid & 3) == 0) {
    double tot = part[tid] + part[tid + 1] + part[tid + 2] + part[tid + 3];
    part[tid] = sqrt(tot) + 1e-8;  // norm + EPS, in f64
  }
  __syncthreads();
  for (int idx = tid; idx < 64 * CC; idx += 256) {
    int r = idx >> 8;
    int c = idx & (CC - 1);
    S[r][c] = (float)((double)S[r][c] / part[r << 2]);
  }
  __syncthreads();
}

__global__ __launch_bounds__(256) void build_dist_kernel(
    const float* __restrict__ x, float* __restrict__ dall,
    unsigned long long* __restrict__ rkall) {
  __shared__ float A[64][TPAD];
  __shared__ float Bs[64][TPAD];
  __shared__ double part[256];
  __shared__ unsigned long long rkl[64];

  int ta = blockIdx.x;   // row tile 0..7
  int b  = blockIdx.y;   // batch
  const float* xb = x + (size_t)b * TT * CC;
  float* d = dall + (size_t)b * TT * TT;
  int tid = threadIdx.x;
  if (tid < 64) rkl[tid] = ~0ull;
  load_norm_tile(xb, ta * 64, A, part, tid);

  int ty = tid & 15;   // col group (contiguous cols -> coalesced float4 stores)
  int tx = tid >> 4;   // row group
  for (int tb = 0; tb < 8; ++tb) {
    __syncthreads();   // previous Bs consumers done
    load_norm_tile(xb, tb * 64, Bs, part, tid);
    double acc[4][4];
#pragma unroll
    for (int ia = 0; ia < 4; ++ia)
#pragma unroll
      for (int ib = 0; ib < 4; ++ib) acc[ia][ib] = 0.0;
    for (int k = 0; k < CC; ++k) {
      double av[4], bv[4];
#pragma unroll
      for (int ia = 0; ia < 4; ++ia) av[ia] = (double)A[4 * tx + ia][k];
#pragma unroll
      for (int ib = 0; ib < 4; ++ib) bv[ib] = (double)Bs[4 * ty + ib][k];
#pragma unroll
      for (int ia = 0; ia < 4; ++ia)
#pragma unroll
        for (int ib = 0; ib < 4; ++ib)
          acc[ia][ib] = fma(av[ia], bv[ib], acc[ia][ib]);
    }
#pragma unroll
    for (int ia = 0; ia < 4; ++ia) {
      int gr = ta * 64 + 4 * tx + ia;
      int gcBase = tb * 64 + 4 * ty;
      float vt[4];
      unsigned long long key = ~0ull;
#pragma unroll
      for (int ib = 0; ib < 4; ++ib) {
        int gc = gcBase + ib;
        float v = (gr == gc) ? INFV : (float)(1.0 - acc[ia][ib]);
        vt[ib] = v;
        unsigned long long kk = packkey(v, (unsigned)gc);
        if (kk < key) key = kk;
      }
      *(float4*)(&d[(size_t)gr * TT + gcBase]) =
          make_float4(vt[0], vt[1], vt[2], vt[3]);
#pragma unroll
      for (int off = 1; off < 16; off <<= 1) {
        unsigned long long o = __shfl_xor(key, off, 64);
        if (o < key) key = o;
      }
      if (ty == 0) atomicMin(&rkl[4 * tx + ia], key);
    }
  }
  __syncthreads();
  if (tid < 64) rkall[(size_t)b * TT + ta * 64 + tid] = rkl[tid];
}

// ---------------- Phase 2: agglomerative merging, 4 waves / batch ----------------
// Skeleton = round 7 (measured best, 1369 us, absmax 0.0): 4 barriers/iter,
// cross-wave rescan distribution. Two changes, each with a clear mechanism:
//  (1) NO col-j kill stores. Dead columns hold stale finite values in memory;
//      every reader masks them to INFV via the aliveM bitmask (round-4-proven
//      decision-equivalent; in the 4-wave layout the mask is 1 LDS word +
//      2 bit tests per thread). Halves scattered stores -> halves B3 drain
//      and WRITE_SIZE.
//  (2) Rescan rows PRELOADED at the top of P2 (rlist complete after B2),
//      before the stores issue; loads fly across P2+B3 and are consumed in
//      P3 with patch c==i -> nvs[rr] (the only address racing this iter's
//      stores; dword stores don't tear) and dead-col masking.
// nresc/rlist double-buffered by iter parity (zero next buffer in P0).
// Merge arithmetic / key packing / tie-breaks bitwise-identical to rounds 2/7.
__global__ __launch_bounds__(256) void agglom_kernel(
    const int* __restrict__ ncp, float* __restrict__ dall,
    const unsigned long long* __restrict__ rkall, int* __restrict__ outp) {
  __shared__ unsigned long long rk[TT];
  __shared__ float sizes[TT];
  __shared__ float nvs[TT];
  __shared__ int assign[TT];
  __shared__ int rankArr[TT];
  __shared__ int rlist[2][TT];
  __shared__ unsigned aliveM[TT / 32];    // bit c = col c alive
  __shared__ unsigned long long pm[4];    // per-wave argmin partials
  __shared__ unsigned long long pmi[4];   // per-wave row-i-min partials
  __shared__ int wsum[4];
  __shared__ int nresc[2];

  int b = blockIdx.x;
  int tid = threadIdx.x;
  int lane = tid & 63;
  int w = tid >> 6;
  float* d = dall + (size_t)b * TT * TT;
  int rA = tid * 2, rB = rA + 1;          // this thread's owned rows / cols

  rk[rA] = rkall[(size_t)b * TT + rA];
  rk[rB] = rkall[(size_t)b * TT + rB];
  sizes[rA] = 1.0f; sizes[rB] = 1.0f;
  assign[rA] = rA;  assign[rB] = rB;
  if (tid < TT / 32) aliveM[tid] = 0xFFFFFFFFu;
  if (tid < 2) nresc[tid] = 0;
  int K = ncp[0];
  if (K > TT) K = TT;
  if (K < 1) K = 1;
  int nm = TT - K;
  __syncthreads();

  for (int iter = 0; iter < nm; ++iter) {
    int buf = iter & 1;
    // ---- P0: global argmin over cached row keys, (val,row) lexicographic
    unsigned long long kA =
        (rk[rA] & 0xFFFFFFFF00000000ull) | (unsigned long long)(unsigned)rA;
    unsigned long long kB =
        (rk[rB] & 0xFFFFFFFF00000000ull) | (unsigned long long)(unsigned)rB;
    unsigned long long best = kA < kB ? kA : kB;
    best = wave_min_u64(best);
    if (lane == 0) pm[w] = best;
    if (tid == 0) nresc[buf ^ 1] = 0;     // zero NEXT iter's counter (own buf
                                          // already zeroed two iters ago)
    __syncthreads();                                   // B1
    best = pm[0];
    if (pm[1] < best) best = pm[1];
    if (pm[2] < best) best = pm[2];
    if (pm[3] < best) best = pm[3];
    int i = (int)(best & 0xFFFFFFFFull);   // smallest flat index => row wins tie
    int j = (int)(rk[i] & 0xFFFFFFFFull);  // its first-min column (j > i)
    float ni = sizes[i], nj = sizes[j];
    float denom = ni + nj;

    // ---- P1: row i/j loads; newrow; flag pass -> rlist[buf]
    float2 a2 = *(const float2*)(d + (size_t)i * TT + rA);
    float2 b2 = *(const float2*)(d + (size_t)j * TT + rA);

    // flags from pre-update rk (this iter's rk[i]/rk[j] writes happen in P2)
    unsigned fl = 0;
    if (rA != i && rA != j && sizes[rA] > 0.0f) {
      unsigned c = (unsigned)(rk[rA] & 0xFFFFFFFFull);
      if (c == (unsigned)i || c == (unsigned)j) fl |= 1u;
    }
    if (rB != i && rB != j && sizes[rB] > 0.0f) {
      unsigned c = (unsigned)(rk[rB] & 0xFFFFFFFFull);
      if (c == (unsigned)i || c == (unsigned)j) fl |= 2u;
    }
    if (fl & 1u) { int p = atomicAdd(&nresc[buf], 1); rlist[buf][p] = rA; }
    if (fl & 2u) { int p = atomicAdd(&nresc[buf], 1); rlist[buf][p] = rB; }

    // dead-col mask for own 2 cols (pre-clear: j's bit still set, c==j explicit)
    unsigned aw = aliveM[rA >> 5];
    bool alA = (aw >> (rA & 31)) & 1u;
    bool alB = (aw >> (rB & 31)) & 1u;

    float v0 = (ni * a2.x + nj * b2.x) / denom;   // contract(off): mul,mul,add,div
    float v1 = (ni * a2.y + nj * b2.y) / denom;
    float w0 = (rA == i || rA == j || !alA) ? INFV : v0;
    float w1 = (rB == i || rB == j || !alB) ? INFV : v1;
    nvs[rA] = w0; nvs[rB] = w1;
    unsigned long long ik = packkey(w0, (unsigned)rA);
    unsigned long long ik2 = packkey(w1, (unsigned)rB);
    if (ik2 < ik) ik = ik2;
    ik = wave_min_u64(ik);
    if (lane == 0) pmi[w] = ik;
    __syncthreads();                                   // B2 (nvs, pmi, rlist ready)

    // ---- P2: FIRST issue rescan preloads (fly across stores + B3 drain),
    // then stores + bookkeeping + lazy
    int nr = nresc[buf];
    int er0 = (2 * w < nr) ? rlist[buf][2 * w] : -1;
    int er1 = (2 * w + 1 < nr) ? rlist[buf][2 * w + 1] : -1;
    float4 pa0, pb0, pa1, pb1;
    if (er0 >= 0) {
      const float4* p = (const float4*)(d + (size_t)er0 * TT);
      pa0 = p[lane * 2]; pb0 = p[lane * 2 + 1];
    }
    if (er1 >= 0) {
      const float4* p = (const float4*)(d + (size_t)er1 * TT);
      pa1 = p[lane * 2]; pb1 = p[lane * 2 + 1];
    }

    *(float2*)(d + (size_t)i * TT + rA) = make_float2(w0, w1);  // row i
    d[(size_t)rA * TT + i] = w0;                                // col i scatter
    d[(size_t)rB * TT + i] = w1;                                // (no col-j kill)
    if (tid == 0) {
      unsigned long long ikey = pmi[0];
      if (pmi[1] < ikey) ikey = pmi[1];
      if (pmi[2] < ikey) ikey = pmi[2];
      if (pmi[3] < ikey) ikey = pmi[3];
      sizes[i] = denom;
      sizes[j] = 0.0f;
      rk[i] = ikey;
      rk[j] = packkey(INFV, 0xFFFFFFFFu);
      aliveM[j >> 5] &= ~(1u << (j & 31));   // col j dies
    }
#pragma unroll
    for (int t = 0; t < 2; ++t) {
      int r = rA + t;
      if (!((fl >> t) & 1u) && r != i && r != j && sizes[r] > 0.0f) {
        unsigned long long cur = rk[r];
        unsigned long long nk = packkey(nvs[r], (unsigned)i);
        if (nk < cur) rk[r] = nk;          // equal-val smaller-col handled
      }
      if (assign[r] == j) assign[r] = i;
    }
    __syncthreads();                               // B3 (stores drained, aliveM set)

    // ---- P3: consume preloads; patch c==i -> nvs, c==j -> INFV, dead -> INFV
    int cb = lane * 8;
    unsigned aw2 = aliveM[lane >> 2];              // post-clear (j bit off)
#define PATCH_FOLD(RR, V0, V1)                                                \
    {                                                                         \
      float pv = nvs[RR];                                                     \
      unsigned long long key = ~0ull, kk;                                     \
      _Pragma("unroll") for (int t = 0; t < 8; ++t) {                         \
        int c = cb + t;                                                       \
        bool alive = (aw2 >> (((lane & 3) << 3) + t)) & 1u;                   \
        float e = t < 4 ? (&V0.x)[t] : (&V1.x)[t - 4];                        \
        e = (c == i) ? pv : ((c == j || !alive) ? INFV : e);                  \
        kk = packkey(e, (unsigned)c); if (kk < key) key = kk;                 \
      }                                                                       \
      key = wave_min_u64(key);                                                \
      if (lane == 0) rk[RR] = key;                                            \
    }
    if (er0 >= 0) PATCH_FOLD(er0, pa0, pb0);
    if (er1 >= 0) PATCH_FOLD(er1, pa1, pb1);
    // leftovers (>8 rescans, rare): direct loads + same patch/mask
    for (int q = 8 + w; q < nr; q += 4) {
      int rr = rlist[buf][q];
      const float4* p = (const float4*)(d + (size_t)rr * TT);
      float4 x0 = p[lane * 2], x1 = p[lane * 2 + 1];
      PATCH_FOLD(rr, x0, x1);
    }
#undef PATCH_FOLD
    __syncthreads();                               // B4 (rescan rk visible)
  }

  // ---- canonical relabel: assign[t] == min original index of t's cluster
  int f0 = (assign[rA] == rA) ? 1 : 0;
  int f1 = (assign[rB] == rB) ? 1 : 0;
  int c = f0 + f1;
  int incl = c;
#pragma unroll
  for (int off = 1; off < 64; off <<= 1) {
    int o = __shfl_up(incl, (unsigned)off, 64);
    if (lane >= off) incl += o;
  }
  if (lane == 63) wsum[w] = incl;
  __syncthreads();
  int base = incl - c;
  for (int q = 0; q < w; ++q) base += wsum[q];
  if (f0) rankArr[rA] = base;
  if (f1) rankArr[rB] = base + f0;
  __syncthreads();
  outp[(size_t)b * TT + rA] = rankArr[assign[rA]];
  outp[(size_t)b * TT + rB] = rankArr[assign[rB]];
}

extern "C" void kernel_launch(void* const* d_in, const int* in_sizes, int n_in,
                              void* d_out, int out_size, void* d_ws, size_t ws_size,
                              hipStream_t stream) {
  const float* x = (const float*)d_in[0];
  const int* ncp = (const int*)d_in[1];
  int B = in_sizes[0] / (TT * CC);
  float* dall = (float*)d_ws;                                   // B * 512*512 f32 (64 MiB)
  unsigned long long* rkall =
      (unsigned long long*)((char*)d_ws + (size_t)B * TT * TT * sizeof(float));
  int* outp = (int*)d_out;

  dim3 g1(TT / 64, B);
  build_dist_kernel<<<g1, 256, 0, stream>>>(x, dall, rkall);
  agglom_kernel<<<B, 256, 0, stream>>>(ncp, dall, rkall, outp);
}